// Round 5
// baseline (1932.964 us; speedup 1.0000x reference)
//
#include <hip/hip_runtime.h>
#include <math.h>

#define NN 50000
#define NE 640000
#define DIM 128
#define NH 8

typedef unsigned short u16;
typedef __attribute__((ext_vector_type(8))) short short8;
typedef __attribute__((ext_vector_type(4))) float f32x4;

__device__ __forceinline__ float wave_sum64(float v) {
  #pragma unroll
  for (int m = 32; m >= 1; m >>= 1) v += __shfl_xor(v, m, 64);
  return v;
}
__device__ __forceinline__ unsigned bf16pk(float a, float b) {
  unsigned ua = __float_as_uint(a); ua = (ua + 0x7fffu + ((ua >> 16) & 1u)) >> 16;
  unsigned ub = __float_as_uint(b); ub = (ub + 0x7fffu + ((ub >> 16) & 1u)) & 0xffff0000u;
  return ua | ub;
}
__device__ __forceinline__ u16 bf16c(float x) {
  unsigned u = __float_as_uint(x);
  return (u16)((u + 0x7fffu + ((u >> 16) & 1u)) >> 16);
}
__device__ __forceinline__ float bf_lo(unsigned v) { return __uint_as_float(v << 16); }
__device__ __forceinline__ float bf_hi(unsigned v) { return __uint_as_float(v & 0xffff0000u); }

#define AS1(p) ((const __attribute__((address_space(1))) unsigned*)(p))
#define AS3(p) ((__attribute__((address_space(3))) unsigned*)(p))

// ---------------------------------------------------------------------------
// Fused prep: node f32->bf16 pack, 4x weight transpose+cvt, CSR degree count
// ---------------------------------------------------------------------------
__global__ __launch_bounds__(256) void prep_k(
    const float* __restrict__ node, unsigned* __restrict__ node16,
    const float* __restrict__ Wq, const float* __restrict__ Wk,
    const float* __restrict__ W1, const float* __restrict__ W2,
    u16* __restrict__ Wtq, u16* __restrict__ Wtk,
    u16* __restrict__ Wt1, u16* __restrict__ Wt2,
    const int* __restrict__ dst, int* __restrict__ deg) {
  int b = blockIdx.x, tid = threadIdx.x;
  if (b < 12500) {
    int t = b * 256 + tid;                    // t < 3,200,000 exactly
    float2 v = *(const float2*)(node + (size_t)2 * t);
    node16[t] = bf16pk(v.x, v.y);
  } else if (b < 12564) {
    int t = (b - 12500) * 256 + tid;          // 128x128
    int n = t >> 7, k = t & 127;
    Wtq[t] = bf16c(Wq[(size_t)k * 128 + n]);
  } else if (b < 12628) {
    int t = (b - 12564) * 256 + tid;
    int n = t >> 7, k = t & 127;
    Wtk[t] = bf16c(Wk[(size_t)k * 128 + n]);
  } else if (b < 12756) {
    int t = (b - 12628) * 256 + tid;          // K=128,N=256
    int n = t >> 7, k = t & 127;
    Wt1[t] = bf16c(W1[(size_t)k * 256 + n]);
  } else if (b < 12884) {
    int t = (b - 12756) * 256 + tid;          // K=256,N=128
    int n = t >> 8, k = t & 255;
    Wt2[t] = bf16c(W2[(size_t)k * 128 + n]);
  } else {
    int e = (b - 12884) * 256 + tid;          // e < 640,000 exactly
    atomicAdd(&deg[dst[e]], 1);
  }
}

#define SCAN_T 1024
#define SCHUNK 49
__global__ __launch_bounds__(1024) void scan_k(const int* __restrict__ deg,
                                               int* __restrict__ off,
                                               int* __restrict__ cursor) {
  __shared__ int part[SCAN_T];
  int t = threadIdx.x;
  int lo = t * SCHUNK, hi = lo + SCHUNK; if (hi > NN) hi = NN;
  int s = 0;
  for (int i = lo; i < hi; ++i) s += deg[i];
  part[t] = s;
  __syncthreads();
  for (int o = 1; o < SCAN_T; o <<= 1) {
    int v = (t >= o) ? part[t - o] : 0;
    __syncthreads();
    part[t] += v;
    __syncthreads();
  }
  int base = (t == 0) ? 0 : part[t - 1];
  for (int i = lo; i < hi; ++i) {
    off[i] = base; cursor[i] = base; base += deg[i];
  }
  if (t == SCAN_T - 1) off[NN] = part[SCAN_T - 1];
}

__global__ __launch_bounds__(256) void csr_fill_k(const int* __restrict__ dst,
                                                  int* __restrict__ cursor,
                                                  int* __restrict__ eids) {
  int e = blockIdx.x * 256 + threadIdx.x;
  if (e < NE) {
    int p = atomicAdd(&cursor[dst[e]], 1);
    eids[p] = e;
  }
}

// ---------------------------------------------------------------------------
// MFMA GEMM: qb16/kb16 = node16 @ Wq / Wk  (M=NN, K=128, N=128+128)
// T2 swizzle: linear LDS dest via global_load_lds with pre-swizzled SOURCE;
// ds_read addresses XOR (row&7)<<4.
// ---------------------------------------------------------------------------
__global__ __launch_bounds__(256) void qk_mfma_k(
    const u16* __restrict__ A, const u16* __restrict__ Wtq,
    const u16* __restrict__ Wtk, u16* __restrict__ qo,
    u16* __restrict__ ko) {
  __shared__ u16 At[64 * 128];  // 16 KB
  const int wid = threadIdx.x >> 6, l = threadIdx.x & 63;
  const int quad = l >> 4, l16 = l & 15;
  const int c0 = (wid & 1) * 64;
  const u16* wt = (wid < 2) ? Wtq : Wtk;
  u16* ob = (wid < 2) ? qo : ko;
  short8 bfr[4][4];
  #pragma unroll
  for (int ct = 0; ct < 4; ++ct)
    #pragma unroll
    for (int ks = 0; ks < 4; ++ks)
      bfr[ct][ks] = *(const short8*)(wt + (c0 + ct * 16 + l16) * 128 + ks * 32 + quad * 8);
  const int ntiles = (NN + 63) / 64;
  for (int t = blockIdx.x; t < ntiles; t += gridDim.x) {
    const char* gsrc = (const char*)A + (size_t)t * 64 * 128 * 2;
    #pragma unroll
    for (int i = 0; i < 4; ++i) {
      int dbase = wid * 4096 + i * 1024;
      int soff = (dbase + l * 16) ^ ((((i * 4) + (l >> 4)) & 7) << 4);
      __builtin_amdgcn_global_load_lds(AS1(gsrc + soff),
                                       AS3((char*)At + dbase), 16, 0, 0);
    }
    __syncthreads();
    f32x4 acc[4][4];
    #pragma unroll
    for (int rt = 0; rt < 4; ++rt)
      #pragma unroll
      for (int ct = 0; ct < 4; ++ct)
        acc[rt][ct] = (f32x4){0.f, 0.f, 0.f, 0.f};
    #pragma unroll
    for (int ks = 0; ks < 4; ++ks) {
      short8 af[4];
      #pragma unroll
      for (int rt = 0; rt < 4; ++rt) {
        int bo = (((rt * 16 + l16) * 128 + ks * 32 + quad * 8) * 2) ^ ((l16 & 7) << 4);
        af[rt] = *(const short8*)((const char*)At + bo);
      }
      #pragma unroll
      for (int rt = 0; rt < 4; ++rt)
        #pragma unroll
        for (int ct = 0; ct < 4; ++ct)
          acc[rt][ct] = __builtin_amdgcn_mfma_f32_16x16x32_bf16(
              af[rt], bfr[ct][ks], acc[rt][ct], 0, 0, 0);
    }
    __syncthreads();
    #pragma unroll
    for (int rt = 0; rt < 4; ++rt)
      #pragma unroll
      for (int r = 0; r < 4; ++r) {
        int row = t * 64 + rt * 16 + quad * 4 + r;
        if (row < NN) {
          u16* op = ob + (size_t)row * 128 + c0 + l16;
          #pragma unroll
          for (int ct = 0; ct < 4; ++ct) op[ct * 16] = bf16c(acc[rt][ct][r]);
        }
      }
  }
}

// ---------------------------------------------------------------------------
// Fused FFN + final LN: out = LN(relu(hbuf16 @ W1) @ W2 + he)
// ---------------------------------------------------------------------------
__global__ __launch_bounds__(256) void ffn_mfma_k(
    const u16* __restrict__ A, const u16* __restrict__ Wt1,
    const u16* __restrict__ Wt2, const float* __restrict__ he,
    float* __restrict__ outp) {
  __shared__ __align__(16) u16 At[64 * 128];   // 16 KB
  __shared__ __align__(16) u16 Ht[64 * 256];   // 32 KB (swizzled)
  __shared__ float redS[4][64], redQ[4][64];   // 2 KB
  const int wid = threadIdx.x >> 6, l = threadIdx.x & 63;
  const int quad = l >> 4, l16 = l & 15;
  const int c1 = wid * 64;                     // W1 cols of 256
  const int c2 = wid * 32;                     // W2 cols of 128
  const int ntiles = (NN + 63) / 64;
  for (int t = blockIdx.x; t < ntiles; t += gridDim.x) {
    short8 b1f[4][4];
    #pragma unroll
    for (int ct = 0; ct < 4; ++ct)
      #pragma unroll
      for (int ks = 0; ks < 4; ++ks)
        b1f[ct][ks] = *(const short8*)(Wt1 + (c1 + ct * 16 + l16) * 128 + ks * 32 + quad * 8);
    const char* gsrc = (const char*)A + (size_t)t * 64 * 128 * 2;
    #pragma unroll
    for (int i = 0; i < 4; ++i) {
      int dbase = wid * 4096 + i * 1024;
      int soff = (dbase + l * 16) ^ ((((i * 4) + (l >> 4)) & 7) << 4);
      __builtin_amdgcn_global_load_lds(AS1(gsrc + soff),
                                       AS3((char*)At + dbase), 16, 0, 0);
    }
    __syncthreads();                           // [S]
    f32x4 acc1[4][4];
    #pragma unroll
    for (int rt = 0; rt < 4; ++rt)
      #pragma unroll
      for (int ct = 0; ct < 4; ++ct)
        acc1[rt][ct] = (f32x4){0.f, 0.f, 0.f, 0.f};
    #pragma unroll
    for (int ks = 0; ks < 4; ++ks) {
      short8 af[4];
      #pragma unroll
      for (int rt = 0; rt < 4; ++rt) {
        int bo = (((rt * 16 + l16) * 128 + ks * 32 + quad * 8) * 2) ^ ((l16 & 7) << 4);
        af[rt] = *(const short8*)((const char*)At + bo);
      }
      #pragma unroll
      for (int rt = 0; rt < 4; ++rt)
        #pragma unroll
        for (int ct = 0; ct < 4; ++ct)
          acc1[rt][ct] = __builtin_amdgcn_mfma_f32_16x16x32_bf16(
              af[rt], b1f[ct][ks], acc1[rt][ct], 0, 0, 0);
    }
    #pragma unroll
    for (int rt = 0; rt < 4; ++rt)
      #pragma unroll
      for (int r = 0; r < 4; ++r) {
        int row = rt * 16 + quad * 4 + r;
        #pragma unroll
        for (int ct = 0; ct < 4; ++ct) {
          int col = c1 + ct * 16 + l16;
          int bo = (row * 512 + col * 2) ^ ((row & 7) << 4);
          *(u16*)((char*)Ht + bo) = bf16c(fmaxf(acc1[rt][ct][r], 0.f));
        }
      }
    __syncthreads();                           // [H]
    short8 b2f[2][8];
    #pragma unroll
    for (int ct = 0; ct < 2; ++ct)
      #pragma unroll
      for (int ks = 0; ks < 8; ++ks)
        b2f[ct][ks] = *(const short8*)(Wt2 + (c2 + ct * 16 + l16) * 256 + ks * 32 + quad * 8);
    f32x4 acc2[4][2];
    #pragma unroll
    for (int rt = 0; rt < 4; ++rt)
      #pragma unroll
      for (int ct = 0; ct < 2; ++ct)
        acc2[rt][ct] = (f32x4){0.f, 0.f, 0.f, 0.f};
    #pragma unroll
    for (int ks = 0; ks < 8; ++ks) {
      short8 af[4];
      #pragma unroll
      for (int rt = 0; rt < 4; ++rt) {
        int bo = ((rt * 16 + l16) * 512 + ks * 64 + quad * 16) ^ ((l16 & 7) << 4);
        af[rt] = *(const short8*)((const char*)Ht + bo);
      }
      #pragma unroll
      for (int rt = 0; rt < 4; ++rt)
        #pragma unroll
        for (int ct = 0; ct < 2; ++ct)
          acc2[rt][ct] = __builtin_amdgcn_mfma_f32_16x16x32_bf16(
              af[rt], b2f[ct][ks], acc2[rt][ct], 0, 0, 0);
    }
    #pragma unroll
    for (int rt = 0; rt < 4; ++rt)
      #pragma unroll
      for (int r = 0; r < 4; ++r) {
        int row = rt * 16 + quad * 4 + r;
        int grow = t * 64 + row;
        float h0 = 0.f, h1 = 0.f;
        if (grow < NN) {
          h0 = he[(size_t)grow * 128 + c2 + l16];
          h1 = he[(size_t)grow * 128 + c2 + 16 + l16];
        }
        float z0 = acc2[rt][0][r] + h0;
        float z1 = acc2[rt][1][r] + h1;
        acc2[rt][0][r] = z0; acc2[rt][1][r] = z1;
        float ps = z0 + z1;
        float pq = fmaf(z0, z0, z1 * z1);
        ps += __shfl_xor(ps, 1, 64);  pq += __shfl_xor(pq, 1, 64);
        ps += __shfl_xor(ps, 2, 64);  pq += __shfl_xor(pq, 2, 64);
        ps += __shfl_xor(ps, 4, 64);  pq += __shfl_xor(pq, 4, 64);
        ps += __shfl_xor(ps, 8, 64);  pq += __shfl_xor(pq, 8, 64);
        if (l16 == 0) { redS[wid][row] = ps; redQ[wid][row] = pq; }
      }
    __syncthreads();                           // [R]
    #pragma unroll
    for (int rt = 0; rt < 4; ++rt)
      #pragma unroll
      for (int r = 0; r < 4; ++r) {
        int row = rt * 16 + quad * 4 + r;
        int grow = t * 64 + row;
        float s4 = redS[0][row] + redS[1][row] + redS[2][row] + redS[3][row];
        float q4 = redQ[0][row] + redQ[1][row] + redQ[2][row] + redQ[3][row];
        float mu = s4 * (1.f / 128.f);
        float vr = q4 * (1.f / 128.f) - mu * mu;
        float rs = rsqrtf(vr + 1e-5f);
        if (grow < NN) {
          outp[(size_t)grow * 128 + c2 + l16]      = (acc2[rt][0][r] - mu) * rs;
          outp[(size_t)grow * 128 + c2 + 16 + l16] = (acc2[rt][1][r] - mu) * rs;
        }
      }
  }
}

// ---------------------------------------------------------------------------
// Per-node FUSED attention: per-edge score (k[src].q[n] per head, 8-lane-group
// shfl reduce) + exp + online denominator + weighted bond gather, all in one
// pass (static-unrolled groups of 8, zero scratch). Then Wv projection (LDS),
// beta gate + LN1.  q loaded once per node; k rows L2-hot (12.8MB).
// ---------------------------------------------------------------------------
__global__ __launch_bounds__(512, 6) void node_attn_k(
    const float* __restrict__ bond, const float* __restrict__ WvG,
    const unsigned* __restrict__ qb16, const unsigned* __restrict__ kb16,
    const float* __restrict__ ba, const int* __restrict__ srcv,
    const int* __restrict__ off, const int* __restrict__ eids,
    const float* __restrict__ x, const float* __restrict__ Wdis,
    const float* __restrict__ Wb, const float* __restrict__ g1,
    const float* __restrict__ b1, float* __restrict__ he,
    unsigned* __restrict__ hbuf16) {
  __shared__ unsigned Wvpk[DIM * 64];                 // 32 KB, packed cols (c, c+64)
  __shared__ __align__(16) unsigned gbuf[8][NH][68];  // 17.4 KB, 16B-aligned rows
  for (int t = threadIdx.x; t < DIM * 64; t += 512) {
    int i = t >> 6, c = t & 63;
    Wvpk[t] = bf16pk(WvG[i * DIM + c], WvG[i * DIM + c + 64]);
  }
  __syncthreads();
  const int wid = threadIdx.x >> 6, l = threadIdx.x & 63;
  const float wdis_l = Wdis[l >> 3];          // head for score lanes: l>>3
  const float wb0 = Wb[l],         wb1 = Wb[l + 64];
  const float wb2 = Wb[DIM + l],   wb3 = Wb[DIM + l + 64];
  const float wb4 = Wb[2*DIM + l], wb5 = Wb[2*DIM + l + 64];
  const float gl0 = g1[l], gl1 = g1[l + 64];
  const float bl0 = b1[l], bl1 = b1[l + 64];

  for (int n = blockIdx.x * 8 + wid; n < NN; n += gridDim.x * 8) {
    int o0 = __builtin_amdgcn_readfirstlane(off[n]);
    int o1 = __builtin_amdgcn_readfirstlane(off[n + 1]);
    int deg = o1 - o0;
    unsigned ql = qb16[(size_t)n * 64 + l];   // q row: cols (2l, 2l+1)
    float qlo = bf_lo(ql), qhi = bf_hi(ql);
    float acc[16];
    #pragma unroll
    for (int i = 0; i < 16; ++i) acc[i] = 0.f;
    float dsum = 0.f;

    for (int g = 0; g < deg; g += 8) {
      int eg[8]; unsigned kc[8]; float2 bc[8];
      #pragma unroll
      for (int s = 0; s < 8; ++s) {
        if (g + s < deg) {
          int e = eids[o0 + g + s];
          eg[s] = e;
          kc[s] = kb16[(size_t)srcv[e] * 64 + l];
          bc[s] = *(const float2*)(bond + (size_t)e * DIM + 2 * l);
        }
      }
      #pragma unroll
      for (int s = 0; s < 8; ++s) {
        if (g + s < deg) {
          // per-head dot: head h covers lanes [8h, 8h+8)
          float p = bf_lo(kc[s]) * qlo;
          p = fmaf(bf_hi(kc[s]), qhi, p);
          p += __shfl_xor(p, 1, 64);
          p += __shfl_xor(p, 2, 64);
          p += __shfl_xor(p, 4, 64);
          float ex = __expf(fmaf(ba[eg[s]], wdis_l, p * 0.25f));
          dsum += ex;
          float a0 = __shfl(ex, 0, 64),  a1 = __shfl(ex, 8, 64);
          float a2 = __shfl(ex, 16, 64), a3 = __shfl(ex, 24, 64);
          float a4 = __shfl(ex, 32, 64), a5 = __shfl(ex, 40, 64);
          float a6 = __shfl(ex, 48, 64), a7 = __shfl(ex, 56, 64);
          float2 bv = bc[s];
          acc[0]  = fmaf(a0, bv.x, acc[0]);  acc[1]  = fmaf(a0, bv.y, acc[1]);
          acc[2]  = fmaf(a1, bv.x, acc[2]);  acc[3]  = fmaf(a1, bv.y, acc[3]);
          acc[4]  = fmaf(a2, bv.x, acc[4]);  acc[5]  = fmaf(a2, bv.y, acc[5]);
          acc[6]  = fmaf(a3, bv.x, acc[6]);  acc[7]  = fmaf(a3, bv.y, acc[7]);
          acc[8]  = fmaf(a4, bv.x, acc[8]);  acc[9]  = fmaf(a4, bv.y, acc[9]);
          acc[10] = fmaf(a5, bv.x, acc[10]); acc[11] = fmaf(a5, bv.y, acc[11]);
          acc[12] = fmaf(a6, bv.x, acc[12]); acc[13] = fmaf(a6, bv.y, acc[13]);
          acc[14] = fmaf(a7, bv.x, acc[14]); acc[15] = fmaf(a7, bv.y, acc[15]);
        }
      }
    }
    // normalize per head: lane group [8h,8h+8) holds dsum for head h
    float rden = 1.f / (dsum + 1e-16f);
    #pragma unroll
    for (int h = 0; h < 8; ++h) {
      float rh = __shfl(rden, 8 * h, 64);
      acc[2 * h] *= rh; acc[2 * h + 1] *= rh;
    }
    // stash g (bf16-packed), wave-private -> no barrier
    #pragma unroll
    for (int h = 0; h < 8; ++h)
      gbuf[wid][h][l] = bf16pk(acc[2 * h], acc[2 * h + 1]);
    // projection: ft cols (l, l+64); heads h0 = l>>4, h1 = 4 + (l>>4)
    int h0 = l >> 4, h1 = 4 + (l >> 4);
    const uint4* gu = (const uint4*)(&gbuf[wid][h0][0]);
    const uint4* gv = (const uint4*)(&gbuf[wid][h1][0]);
    float f0 = 0.f, f1 = 0.f;
    #pragma unroll
    for (int q4 = 0; q4 < 16; ++q4) {
      uint4 U = gu[q4], V = gv[q4];
      #pragma unroll
      for (int j = 0; j < 4; ++j) {
        unsigned u = (j == 0) ? U.x : (j == 1) ? U.y : (j == 2) ? U.z : U.w;
        unsigned v = (j == 0) ? V.x : (j == 1) ? V.y : (j == 2) ? V.z : V.w;
        int ii = q4 * 4 + j;
        unsigned w0 = Wvpk[(2 * ii) * 64 + l];
        unsigned w1 = Wvpk[(2 * ii + 1) * 64 + l];
        f0 = fmaf(bf_lo(u), bf_lo(w0), f0); f0 = fmaf(bf_hi(u), bf_lo(w1), f0);
        f1 = fmaf(bf_lo(v), bf_hi(w0), f1); f1 = fmaf(bf_hi(v), bf_hi(w1), f1);
      }
    }
    // beta gate + LN1
    float x0 = x[(size_t)n * DIM + l], x1 = x[(size_t)n * DIM + l + 64];
    float s = f0 * wb0 + x0 * wb2 + (f0 - x0) * wb4
            + f1 * wb1 + x1 * wb3 + (f1 - x1) * wb5;
    s = wave_sum64(s);
    float beta = 1.f / (1.f + __expf(-s));
    float he0 = beta * x0 + (1.f - beta) * f0;
    float he1 = beta * x1 + (1.f - beta) * f1;
    he[(size_t)n * DIM + l] = he0;
    he[(size_t)n * DIM + l + 64] = he1;
    float mu = wave_sum64(he0 + he1) * (1.f / DIM);
    float vr = wave_sum64(he0 * he0 + he1 * he1) * (1.f / DIM) - mu * mu;
    float rs = rsqrtf(vr + 1e-5f);
    float v0 = (he0 - mu) * rs * gl0 + bl0;
    float v1 = (he1 - mu) * rs * gl1 + bl1;
    // shuffle-transpose to packed bf16 row layout
    int i0 = (2 * l) & 63, i1 = (2 * l + 1) & 63;
    float a0 = __shfl(v0, i0, 64), b0 = __shfl(v1, i0, 64);
    float a1 = __shfl(v0, i1, 64), b1v = __shfl(v1, i1, 64);
    float c0 = (l < 32) ? a0 : b0;
    float c1 = (l < 32) ? a1 : b1v;
    hbuf16[(size_t)n * 64 + l] = bf16pk(c0, c1);
  }
}

// ---------------------------------------------------------------------------
extern "C" void kernel_launch(void* const* d_in, const int* in_sizes, int n_in,
                              void* d_out, int out_size, void* d_ws, size_t ws_size,
                              hipStream_t stream) {
  const float* node = (const float*)d_in[0];
  const float* bond = (const float*)d_in[1];
  const float* ba   = (const float*)d_in[2];
  const int*   src  = (const int*)  d_in[3];
  const int*   dst  = (const int*)  d_in[4];
  const float* Wk   = (const float*)d_in[5];
  const float* Wq   = (const float*)d_in[6];
  const float* Wv   = (const float*)d_in[7];
  const float* Wdis = (const float*)d_in[8];
  const float* Wb   = (const float*)d_in[9];
  const float* g1   = (const float*)d_in[10];
  const float* b1   = (const float*)d_in[11];
  const float* W1   = (const float*)d_in[12];
  const float* W2   = (const float*)d_in[13];
  float* out = (float*)d_out;

  // workspace byte layout:
  //  [0, 13M):      node16 (12.82M)  -> dead after qk_mfma
  //  [13M, 26M):    qb16
  //  [26M, 39M):    kb16 -> hbuf16 (kb16 dead after node_attn... disjoint uses:
  //                 kb16 read + hbuf16 written by same kernel -> SEPARATE now)
  //  [39M, 52M):    hbuf16
  //  [64.6M, 90.2M): he
  //  [90.2M, 90.4M): Wtq/Wtk/Wt1/Wt2
  //  [90.4M, ..):   CSR ints
  char* W = (char*)d_ws;
  u16* node16 = (u16*)(W);
  u16* qb16   = (u16*)(W + 13000000);
  u16* kb16   = (u16*)(W + 26000000);
  u16* hbuf16 = (u16*)(W + 39000000);
  float* he   = (float*)(W + 64600000);
  u16* Wtq    = (u16*)(W + 90200000);
  u16* Wtk    = Wtq + 128 * 128;
  u16* Wt1    = Wtk + 128 * 128;
  u16* Wt2    = Wt1 + 256 * 128;
  int* deg    = (int*)(W + 90400000);
  int* off    = deg + (NN + 1);
  int* cursor = off + (NN + 1);
  int* eids   = cursor + (NN + 1);

  hipMemsetAsync(deg, 0, (size_t)(NN + 1) * 4, stream);

  // fused prep (cvt + 4x wprep + csr count)
  prep_k<<<15384, 256, 0, stream>>>(node, (unsigned*)node16, Wq, Wk, W1, W2,
                                    Wtq, Wtk, Wt1, Wt2, dst, deg);
  scan_k<<<1, 1024, 0, stream>>>(deg, off, cursor);
  csr_fill_k<<<(NE + 255) / 256, 256, 0, stream>>>(dst, cursor, eids);

  const int ntiles = (NN + 63) / 64;  // 782

  // q/k projection (MFMA, swizzled LDS)
  qk_mfma_k<<<ntiles, 256, 0, stream>>>(node16, Wtq, Wtk, qb16, kb16);

  // fused per-node attention (scores + exp + gather) + gate + LN1
  node_attn_k<<<3125, 512, 0, stream>>>(bond, Wv, (const unsigned*)qb16,
                                        (const unsigned*)kb16, ba, src, off,
                                        eids, node, Wdis, Wb, g1, b1, he,
                                        (unsigned*)hbuf16);

  // fused FFN + residual + final LN
  ffn_mfma_k<<<ntiles, 256, 0, stream>>>(hbuf16, Wt1, Wt2, he, out);
}

// Round 6
// 830.505 us; speedup vs baseline: 2.3275x; 2.3275x over previous
//
#include <hip/hip_runtime.h>
#include <math.h>

#define NN 50000
#define NE 640000
#define DIM 128
#define NH 8

typedef unsigned short u16;
typedef __attribute__((ext_vector_type(8))) short short8;
typedef __attribute__((ext_vector_type(4))) float f32x4;

__device__ __forceinline__ float wave_sum64(float v) {
  #pragma unroll
  for (int m = 32; m >= 1; m >>= 1) v += __shfl_xor(v, m, 64);
  return v;
}
__device__ __forceinline__ unsigned bf16pk(float a, float b) {
  unsigned ua = __float_as_uint(a); ua = (ua + 0x7fffu + ((ua >> 16) & 1u)) >> 16;
  unsigned ub = __float_as_uint(b); ub = (ub + 0x7fffu + ((ub >> 16) & 1u)) & 0xffff0000u;
  return ua | ub;
}
__device__ __forceinline__ u16 bf16c(float x) {
  unsigned u = __float_as_uint(x);
  return (u16)((u + 0x7fffu + ((u >> 16) & 1u)) >> 16);
}
__device__ __forceinline__ float bf_lo(unsigned v) { return __uint_as_float(v << 16); }
__device__ __forceinline__ float bf_hi(unsigned v) { return __uint_as_float(v & 0xffff0000u); }

#define AS1(p) ((const __attribute__((address_space(1))) unsigned*)(p))
#define AS3(p) ((__attribute__((address_space(3))) unsigned*)(p))

// ---------------------------------------------------------------------------
// Fused prep: node f32->bf16 pack, 4x weight transpose+cvt, CSR degree count
// ---------------------------------------------------------------------------
__global__ __launch_bounds__(256) void prep_k(
    const float* __restrict__ node, unsigned* __restrict__ node16,
    const float* __restrict__ Wq, const float* __restrict__ Wk,
    const float* __restrict__ W1, const float* __restrict__ W2,
    u16* __restrict__ Wtq, u16* __restrict__ Wtk,
    u16* __restrict__ Wt1, u16* __restrict__ Wt2,
    const int* __restrict__ dst, int* __restrict__ deg) {
  int b = blockIdx.x, tid = threadIdx.x;
  if (b < 12500) {
    int t = b * 256 + tid;                    // t < 3,200,000 exactly
    float2 v = *(const float2*)(node + (size_t)2 * t);
    node16[t] = bf16pk(v.x, v.y);
  } else if (b < 12564) {
    int t = (b - 12500) * 256 + tid;          // 128x128
    int n = t >> 7, k = t & 127;
    Wtq[t] = bf16c(Wq[(size_t)k * 128 + n]);
  } else if (b < 12628) {
    int t = (b - 12564) * 256 + tid;
    int n = t >> 7, k = t & 127;
    Wtk[t] = bf16c(Wk[(size_t)k * 128 + n]);
  } else if (b < 12756) {
    int t = (b - 12628) * 256 + tid;          // K=128,N=256
    int n = t >> 7, k = t & 127;
    Wt1[t] = bf16c(W1[(size_t)k * 256 + n]);
  } else if (b < 12884) {
    int t = (b - 12756) * 256 + tid;          // K=256,N=128
    int n = t >> 8, k = t & 255;
    Wt2[t] = bf16c(W2[(size_t)k * 128 + n]);
  } else {
    int e = (b - 12884) * 256 + tid;          // e < 640,000 exactly
    atomicAdd(&deg[dst[e]], 1);
  }
}

// ---------------------------------------------------------------------------
// Coalesced single-block scan: 49 rounds of 1024, wave shfl-scan + LDS
// cross-wave scan + running base.  (Old version: stride-196B serial reads.)
// ---------------------------------------------------------------------------
#define NROUND 49
__global__ __launch_bounds__(1024) void scan_k(const int* __restrict__ deg,
                                               int* __restrict__ off,
                                               int* __restrict__ cursor) {
  __shared__ int wsum[16];
  __shared__ int roundbase;
  int t = threadIdx.x;
  int lane = t & 63, w = t >> 6;
  if (t == 0) roundbase = 0;
  __syncthreads();
  for (int r = 0; r < NROUND; ++r) {
    int i = r * 1024 + t;
    int v = (i < NN) ? deg[i] : 0;
    int s = v;
    #pragma unroll
    for (int m = 1; m < 64; m <<= 1) {
      int u = __shfl_up(s, m, 64);
      if (lane >= m) s += u;
    }
    if (lane == 63) wsum[w] = s;
    __syncthreads();                       // [A] wsum raw
    if (w == 0) {
      int ws = (lane < 16) ? wsum[lane] : 0;
      #pragma unroll
      for (int m = 1; m < 16; m <<= 1) {
        int u = __shfl_up(ws, m, 64);
        if (lane >= m) ws += u;
      }
      if (lane < 16) wsum[lane] = ws;      // inclusive
    }
    __syncthreads();                       // [B] wsum scanned
    int base = roundbase + ((w > 0) ? wsum[w - 1] : 0);
    int excl = base + s - v;
    if (i < NN) { off[i] = excl; cursor[i] = excl; }
    __syncthreads();                       // [C] all read roundbase/wsum
    if (t == 0) roundbase += wsum[15];
    __syncthreads();                       // [D] roundbase updated
  }
  if (t == 0) off[NN] = roundbase;
}

__global__ __launch_bounds__(256) void csr_fill_k(const int* __restrict__ dst,
                                                  int* __restrict__ cursor,
                                                  int* __restrict__ eids) {
  int e = blockIdx.x * 256 + threadIdx.x;
  if (e < NE) {
    int p = atomicAdd(&cursor[dst[e]], 1);
    eids[p] = e;
  }
}

// ---------------------------------------------------------------------------
// MFMA GEMM: qb16/kb16 = node16 @ Wq / Wk  (M=NN, K=128, N=128+128)
// T2 swizzle: linear LDS dest via global_load_lds with pre-swizzled SOURCE;
// ds_read addresses XOR (row&7)<<4.
// ---------------------------------------------------------------------------
__global__ __launch_bounds__(256) void qk_mfma_k(
    const u16* __restrict__ A, const u16* __restrict__ Wtq,
    const u16* __restrict__ Wtk, u16* __restrict__ qo,
    u16* __restrict__ ko) {
  __shared__ u16 At[64 * 128];  // 16 KB
  const int wid = threadIdx.x >> 6, l = threadIdx.x & 63;
  const int quad = l >> 4, l16 = l & 15;
  const int c0 = (wid & 1) * 64;
  const u16* wt = (wid < 2) ? Wtq : Wtk;
  u16* ob = (wid < 2) ? qo : ko;
  short8 bfr[4][4];
  #pragma unroll
  for (int ct = 0; ct < 4; ++ct)
    #pragma unroll
    for (int ks = 0; ks < 4; ++ks)
      bfr[ct][ks] = *(const short8*)(wt + (c0 + ct * 16 + l16) * 128 + ks * 32 + quad * 8);
  const int ntiles = (NN + 63) / 64;
  for (int t = blockIdx.x; t < ntiles; t += gridDim.x) {
    const char* gsrc = (const char*)A + (size_t)t * 64 * 128 * 2;
    #pragma unroll
    for (int i = 0; i < 4; ++i) {
      int dbase = wid * 4096 + i * 1024;
      int soff = (dbase + l * 16) ^ ((((i * 4) + (l >> 4)) & 7) << 4);
      __builtin_amdgcn_global_load_lds(AS1(gsrc + soff),
                                       AS3((char*)At + dbase), 16, 0, 0);
    }
    __syncthreads();
    f32x4 acc[4][4];
    #pragma unroll
    for (int rt = 0; rt < 4; ++rt)
      #pragma unroll
      for (int ct = 0; ct < 4; ++ct)
        acc[rt][ct] = (f32x4){0.f, 0.f, 0.f, 0.f};
    #pragma unroll
    for (int ks = 0; ks < 4; ++ks) {
      short8 af[4];
      #pragma unroll
      for (int rt = 0; rt < 4; ++rt) {
        int bo = (((rt * 16 + l16) * 128 + ks * 32 + quad * 8) * 2) ^ ((l16 & 7) << 4);
        af[rt] = *(const short8*)((const char*)At + bo);
      }
      #pragma unroll
      for (int rt = 0; rt < 4; ++rt)
        #pragma unroll
        for (int ct = 0; ct < 4; ++ct)
          acc[rt][ct] = __builtin_amdgcn_mfma_f32_16x16x32_bf16(
              af[rt], bfr[ct][ks], acc[rt][ct], 0, 0, 0);
    }
    __syncthreads();
    #pragma unroll
    for (int rt = 0; rt < 4; ++rt)
      #pragma unroll
      for (int r = 0; r < 4; ++r) {
        int row = t * 64 + rt * 16 + quad * 4 + r;
        if (row < NN) {
          u16* op = ob + (size_t)row * 128 + c0 + l16;
          #pragma unroll
          for (int ct = 0; ct < 4; ++ct) op[ct * 16] = bf16c(acc[rt][ct][r]);
        }
      }
  }
}

// ---------------------------------------------------------------------------
// Fused FFN + final LN: out = LN(relu(hbuf16 @ W1) @ W2 + he)
// ---------------------------------------------------------------------------
__global__ __launch_bounds__(256) void ffn_mfma_k(
    const u16* __restrict__ A, const u16* __restrict__ Wt1,
    const u16* __restrict__ Wt2, const float* __restrict__ he,
    float* __restrict__ outp) {
  __shared__ __align__(16) u16 At[64 * 128];   // 16 KB
  __shared__ __align__(16) u16 Ht[64 * 256];   // 32 KB (swizzled)
  __shared__ float redS[4][64], redQ[4][64];   // 2 KB
  const int wid = threadIdx.x >> 6, l = threadIdx.x & 63;
  const int quad = l >> 4, l16 = l & 15;
  const int c1 = wid * 64;                     // W1 cols of 256
  const int c2 = wid * 32;                     // W2 cols of 128
  const int ntiles = (NN + 63) / 64;
  for (int t = blockIdx.x; t < ntiles; t += gridDim.x) {
    short8 b1f[4][4];
    #pragma unroll
    for (int ct = 0; ct < 4; ++ct)
      #pragma unroll
      for (int ks = 0; ks < 4; ++ks)
        b1f[ct][ks] = *(const short8*)(Wt1 + (c1 + ct * 16 + l16) * 128 + ks * 32 + quad * 8);
    const char* gsrc = (const char*)A + (size_t)t * 64 * 128 * 2;
    #pragma unroll
    for (int i = 0; i < 4; ++i) {
      int dbase = wid * 4096 + i * 1024;
      int soff = (dbase + l * 16) ^ ((((i * 4) + (l >> 4)) & 7) << 4);
      __builtin_amdgcn_global_load_lds(AS1(gsrc + soff),
                                       AS3((char*)At + dbase), 16, 0, 0);
    }
    __syncthreads();                           // [S]
    f32x4 acc1[4][4];
    #pragma unroll
    for (int rt = 0; rt < 4; ++rt)
      #pragma unroll
      for (int ct = 0; ct < 4; ++ct)
        acc1[rt][ct] = (f32x4){0.f, 0.f, 0.f, 0.f};
    #pragma unroll
    for (int ks = 0; ks < 4; ++ks) {
      short8 af[4];
      #pragma unroll
      for (int rt = 0; rt < 4; ++rt) {
        int bo = (((rt * 16 + l16) * 128 + ks * 32 + quad * 8) * 2) ^ ((l16 & 7) << 4);
        af[rt] = *(const short8*)((const char*)At + bo);
      }
      #pragma unroll
      for (int rt = 0; rt < 4; ++rt)
        #pragma unroll
        for (int ct = 0; ct < 4; ++ct)
          acc1[rt][ct] = __builtin_amdgcn_mfma_f32_16x16x32_bf16(
              af[rt], b1f[ct][ks], acc1[rt][ct], 0, 0, 0);
    }
    #pragma unroll
    for (int rt = 0; rt < 4; ++rt)
      #pragma unroll
      for (int r = 0; r < 4; ++r) {
        int row = rt * 16 + quad * 4 + r;
        #pragma unroll
        for (int ct = 0; ct < 4; ++ct) {
          int col = c1 + ct * 16 + l16;
          int bo = (row * 512 + col * 2) ^ ((row & 7) << 4);
          *(u16*)((char*)Ht + bo) = bf16c(fmaxf(acc1[rt][ct][r], 0.f));
        }
      }
    __syncthreads();                           // [H]
    short8 b2f[2][8];
    #pragma unroll
    for (int ct = 0; ct < 2; ++ct)
      #pragma unroll
      for (int ks = 0; ks < 8; ++ks)
        b2f[ct][ks] = *(const short8*)(Wt2 + (c2 + ct * 16 + l16) * 256 + ks * 32 + quad * 8);
    f32x4 acc2[4][2];
    #pragma unroll
    for (int rt = 0; rt < 4; ++rt)
      #pragma unroll
      for (int ct = 0; ct < 2; ++ct)
        acc2[rt][ct] = (f32x4){0.f, 0.f, 0.f, 0.f};
    #pragma unroll
    for (int ks = 0; ks < 8; ++ks) {
      short8 af[4];
      #pragma unroll
      for (int rt = 0; rt < 4; ++rt) {
        int bo = ((rt * 16 + l16) * 512 + ks * 64 + quad * 16) ^ ((l16 & 7) << 4);
        af[rt] = *(const short8*)((const char*)Ht + bo);
      }
      #pragma unroll
      for (int rt = 0; rt < 4; ++rt)
        #pragma unroll
        for (int ct = 0; ct < 2; ++ct)
          acc2[rt][ct] = __builtin_amdgcn_mfma_f32_16x16x32_bf16(
              af[rt], b2f[ct][ks], acc2[rt][ct], 0, 0, 0);
    }
    #pragma unroll
    for (int rt = 0; rt < 4; ++rt)
      #pragma unroll
      for (int r = 0; r < 4; ++r) {
        int row = rt * 16 + quad * 4 + r;
        int grow = t * 64 + row;
        float h0 = 0.f, h1 = 0.f;
        if (grow < NN) {
          h0 = he[(size_t)grow * 128 + c2 + l16];
          h1 = he[(size_t)grow * 128 + c2 + 16 + l16];
        }
        float z0 = acc2[rt][0][r] + h0;
        float z1 = acc2[rt][1][r] + h1;
        acc2[rt][0][r] = z0; acc2[rt][1][r] = z1;
        float ps = z0 + z1;
        float pq = fmaf(z0, z0, z1 * z1);
        ps += __shfl_xor(ps, 1, 64);  pq += __shfl_xor(pq, 1, 64);
        ps += __shfl_xor(ps, 2, 64);  pq += __shfl_xor(pq, 2, 64);
        ps += __shfl_xor(ps, 4, 64);  pq += __shfl_xor(pq, 4, 64);
        ps += __shfl_xor(ps, 8, 64);  pq += __shfl_xor(pq, 8, 64);
        if (l16 == 0) { redS[wid][row] = ps; redQ[wid][row] = pq; }
      }
    __syncthreads();                           // [R]
    #pragma unroll
    for (int rt = 0; rt < 4; ++rt)
      #pragma unroll
      for (int r = 0; r < 4; ++r) {
        int row = rt * 16 + quad * 4 + r;
        int grow = t * 64 + row;
        float s4 = redS[0][row] + redS[1][row] + redS[2][row] + redS[3][row];
        float q4 = redQ[0][row] + redQ[1][row] + redQ[2][row] + redQ[3][row];
        float mu = s4 * (1.f / 128.f);
        float vr = q4 * (1.f / 128.f) - mu * mu;
        float rs = rsqrtf(vr + 1e-5f);
        if (grow < NN) {
          outp[(size_t)grow * 128 + c2 + l16]      = (acc2[rt][0][r] - mu) * rs;
          outp[(size_t)grow * 128 + c2 + 16 + l16] = (acc2[rt][1][r] - mu) * rs;
        }
      }
  }
}

// ---------------------------------------------------------------------------
// Edge exp in CSR order: exs[p*8+h] = exp(dot(k[src],q[dst])_h/4 + ba*Wdis)
// coalesced writes; e = eids[p].  (no max-subtraction: logits bounded)
// ---------------------------------------------------------------------------
__global__ __launch_bounds__(256) void edge_exp_k(
    const unsigned* __restrict__ kb16, const unsigned* __restrict__ qb16,
    const float* __restrict__ ba, const int* __restrict__ src,
    const int* __restrict__ dst, const float* __restrict__ Wdis,
    const int* __restrict__ eids, float* __restrict__ exs) {
  int idx = blockIdx.x * 256 + threadIdx.x;
  if (idx >= NE * NH) return;
  int p = idx >> 3, h = idx & 7;
  int e = eids[p];
  int s = src[e], t = dst[e];
  const uint4* kp = (const uint4*)(kb16 + (size_t)s * 64 + h * 8);
  const uint4* qp = (const uint4*)(qb16 + (size_t)t * 64 + h * 8);
  uint4 A0 = kp[0], A1 = kp[1];
  uint4 B0 = qp[0], B1 = qp[1];
  float sc = 0.f;
  sc = fmaf(bf_lo(A0.x), bf_lo(B0.x), sc); sc = fmaf(bf_hi(A0.x), bf_hi(B0.x), sc);
  sc = fmaf(bf_lo(A0.y), bf_lo(B0.y), sc); sc = fmaf(bf_hi(A0.y), bf_hi(B0.y), sc);
  sc = fmaf(bf_lo(A0.z), bf_lo(B0.z), sc); sc = fmaf(bf_hi(A0.z), bf_hi(B0.z), sc);
  sc = fmaf(bf_lo(A0.w), bf_lo(B0.w), sc); sc = fmaf(bf_hi(A0.w), bf_hi(B0.w), sc);
  sc = fmaf(bf_lo(A1.x), bf_lo(B1.x), sc); sc = fmaf(bf_hi(A1.x), bf_hi(B1.x), sc);
  sc = fmaf(bf_lo(A1.y), bf_lo(B1.y), sc); sc = fmaf(bf_hi(A1.y), bf_hi(B1.y), sc);
  sc = fmaf(bf_lo(A1.z), bf_lo(B1.z), sc); sc = fmaf(bf_hi(A1.z), bf_hi(B1.z), sc);
  sc = fmaf(bf_lo(A1.w), bf_lo(B1.w), sc); sc = fmaf(bf_hi(A1.w), bf_hi(B1.w), sc);
  exs[idx] = __expf(sc * 0.25f + ba[e] * Wdis[h]);
}

// ---------------------------------------------------------------------------
// Per-node: weighted bond gather, static-unrolled prefetch depth 16 (covers
// ~85% of nodes in one batch; zero dynamic indexing -> zero scratch),
// denominator folded in (exs float4s wave-uniform), Wv projection (LDS),
// beta gate + LN1.  512 thr; launch_bounds(512,4) -> VGPR cap 128.
// ---------------------------------------------------------------------------
__global__ __launch_bounds__(512, 4) void node_attn_k(
    const float* __restrict__ bond, const float* __restrict__ WvG,
    const float* __restrict__ exs, const int* __restrict__ off,
    const int* __restrict__ eids, const float* __restrict__ x,
    const float* __restrict__ Wb, const float* __restrict__ g1,
    const float* __restrict__ b1, float* __restrict__ he,
    unsigned* __restrict__ hbuf16) {
  __shared__ unsigned Wvpk[DIM * 64];       // 32 KB, packed cols (c, c+64)
  __shared__ unsigned gbuf[8][NH][67];      // bf16-packed g, pad 67
  for (int t = threadIdx.x; t < DIM * 64; t += 512) {
    int i = t >> 6, c = t & 63;
    Wvpk[t] = bf16pk(WvG[i * DIM + c], WvG[i * DIM + c + 64]);
  }
  __syncthreads();
  const int wid = threadIdx.x >> 6, l = threadIdx.x & 63;
  const int hh = l & 7;
  const float wb0 = Wb[l],         wb1 = Wb[l + 64];
  const float wb2 = Wb[DIM + l],   wb3 = Wb[DIM + l + 64];
  const float wb4 = Wb[2*DIM + l], wb5 = Wb[2*DIM + l + 64];
  const float gl0 = g1[l], gl1 = g1[l + 64];
  const float bl0 = b1[l], bl1 = b1[l + 64];

  for (int n = blockIdx.x * 8 + wid; n < NN; n += gridDim.x * 8) {
    int o0 = __builtin_amdgcn_readfirstlane(off[n]);
    int o1 = __builtin_amdgcn_readfirstlane(off[n + 1]);
    int deg = o1 - o0;
    float acc[16];
    #pragma unroll
    for (int i = 0; i < 16; ++i) acc[i] = 0.f;
    float d0 = 0.f, d1 = 0.f, d2 = 0.f, d3 = 0.f;
    float d4 = 0.f, d5 = 0.f, d6 = 0.f, d7 = 0.f;

    for (int g = 0; g < deg; g += 16) {
      float2 bc[16];
      #pragma unroll
      for (int s = 0; s < 16; ++s) {
        if (g + s < deg) {
          int e = eids[o0 + g + s];
          bc[s] = *(const float2*)(bond + (size_t)e * DIM + 2 * l);
        }
      }
      #pragma unroll
      for (int s = 0; s < 16; ++s) {
        if (g + s < deg) {
          const float4* ep = (const float4*)(exs) + (size_t)(o0 + g + s) * 2;
          float4 ea = ep[0], eb = ep[1];   // wave-uniform, L1-hot
          d0 += ea.x; d1 += ea.y; d2 += ea.z; d3 += ea.w;
          d4 += eb.x; d5 += eb.y; d6 += eb.z; d7 += eb.w;
          float2 bv = bc[s];
          acc[0]  = fmaf(ea.x, bv.x, acc[0]);  acc[1]  = fmaf(ea.x, bv.y, acc[1]);
          acc[2]  = fmaf(ea.y, bv.x, acc[2]);  acc[3]  = fmaf(ea.y, bv.y, acc[3]);
          acc[4]  = fmaf(ea.z, bv.x, acc[4]);  acc[5]  = fmaf(ea.z, bv.y, acc[5]);
          acc[6]  = fmaf(ea.w, bv.x, acc[6]);  acc[7]  = fmaf(ea.w, bv.y, acc[7]);
          acc[8]  = fmaf(eb.x, bv.x, acc[8]);  acc[9]  = fmaf(eb.x, bv.y, acc[9]);
          acc[10] = fmaf(eb.y, bv.x, acc[10]); acc[11] = fmaf(eb.y, bv.y, acc[11]);
          acc[12] = fmaf(eb.z, bv.x, acc[12]); acc[13] = fmaf(eb.z, bv.y, acc[13]);
          acc[14] = fmaf(eb.w, bv.x, acc[14]); acc[15] = fmaf(eb.w, bv.y, acc[15]);
        }
      }
    }
    // select this lane's head denominator (hh = l&7), normalize
    float dsa = (hh & 1) ? d1 : d0, dsb = (hh & 1) ? d3 : d2;
    float dsc = (hh & 1) ? d5 : d4, dsd = (hh & 1) ? d7 : d6;
    float dse = (hh & 2) ? dsb : dsa, dsf = (hh & 2) ? dsd : dsc;
    float dsel = (hh & 4) ? dsf : dse;
    float rden = 1.f / (dsel + 1e-16f);
    #pragma unroll
    for (int h = 0; h < 8; ++h) {
      float rh = __shfl(rden, h, 64);
      acc[2 * h] *= rh; acc[2 * h + 1] *= rh;
    }
    // stash g (bf16-packed, padded), wave-private -> no barrier
    #pragma unroll
    for (int h = 0; h < 8; ++h)
      gbuf[wid][h][l] = bf16pk(acc[2 * h], acc[2 * h + 1]);
    // projection: ft cols (l, l+64); heads h0 = l>>4, h1 = 4 + (l>>4)
    int h0 = l >> 4, h1 = 4 + (l >> 4);
    float f0 = 0.f, f1 = 0.f;
    #pragma unroll 8
    for (int ii = 0; ii < 64; ++ii) {
      unsigned u = gbuf[wid][h0][ii];
      unsigned v = gbuf[wid][h1][ii];
      unsigned w0 = Wvpk[(2 * ii) * 64 + l];
      unsigned w1 = Wvpk[(2 * ii + 1) * 64 + l];
      f0 = fmaf(bf_lo(u), bf_lo(w0), f0); f0 = fmaf(bf_hi(u), bf_lo(w1), f0);
      f1 = fmaf(bf_lo(v), bf_hi(w0), f1); f1 = fmaf(bf_hi(v), bf_hi(w1), f1);
    }
    // beta gate + LN1
    float x0 = x[(size_t)n * DIM + l], x1 = x[(size_t)n * DIM + l + 64];
    float s = f0 * wb0 + x0 * wb2 + (f0 - x0) * wb4
            + f1 * wb1 + x1 * wb3 + (f1 - x1) * wb5;
    s = wave_sum64(s);
    float beta = 1.f / (1.f + __expf(-s));
    float he0 = beta * x0 + (1.f - beta) * f0;
    float he1 = beta * x1 + (1.f - beta) * f1;
    he[(size_t)n * DIM + l] = he0;
    he[(size_t)n * DIM + l + 64] = he1;
    float mu = wave_sum64(he0 + he1) * (1.f / DIM);
    float vr = wave_sum64(he0 * he0 + he1 * he1) * (1.f / DIM) - mu * mu;
    float rs = rsqrtf(vr + 1e-5f);
    float v0 = (he0 - mu) * rs * gl0 + bl0;
    float v1 = (he1 - mu) * rs * gl1 + bl1;
    // shuffle-transpose to packed bf16 row layout: uint l holds cols (2l,2l+1)
    int i0 = (2 * l) & 63, i1 = (2 * l + 1) & 63;
    float a0 = __shfl(v0, i0, 64), b0 = __shfl(v1, i0, 64);
    float a1 = __shfl(v0, i1, 64), b1v = __shfl(v1, i1, 64);
    float c0 = (l < 32) ? a0 : b0;
    float c1 = (l < 32) ? a1 : b1v;
    hbuf16[(size_t)n * 64 + l] = bf16pk(c0, c1);
  }
}

// ---------------------------------------------------------------------------
extern "C" void kernel_launch(void* const* d_in, const int* in_sizes, int n_in,
                              void* d_out, int out_size, void* d_ws, size_t ws_size,
                              hipStream_t stream) {
  const float* node = (const float*)d_in[0];
  const float* bond = (const float*)d_in[1];
  const float* ba   = (const float*)d_in[2];
  const int*   src  = (const int*)  d_in[3];
  const int*   dst  = (const int*)  d_in[4];
  const float* Wk   = (const float*)d_in[5];
  const float* Wq   = (const float*)d_in[6];
  const float* Wv   = (const float*)d_in[7];
  const float* Wdis = (const float*)d_in[8];
  const float* Wb   = (const float*)d_in[9];
  const float* g1   = (const float*)d_in[10];
  const float* b1   = (const float*)d_in[11];
  const float* W1   = (const float*)d_in[12];
  const float* W2   = (const float*)d_in[13];
  float* out = (float*)d_out;

  // workspace byte layout (identical to the 858-us passing run):
  //  [0, 13M):      node16 (12.82M)  -> dead after qk_mfma
  //  [13M, 26M):    qb16
  //  [26M, 39M):    kb16 -> hbuf16 (kb16 dead after edge_exp)
  //  [39M, 59.5M):  exs (20.48M)
  //  [64.6M, 90.2M): he
  //  [90.2M, 90.4M): Wtq/Wtk/Wt1/Wt2
  //  [90.4M, ..):   CSR ints
  char* W = (char*)d_ws;
  u16* node16 = (u16*)(W);
  u16* qb16   = (u16*)(W + 13000000);
  u16* kb16   = (u16*)(W + 26000000);
  u16* hbuf16 = (u16*)(W + 26000000);
  float* exs  = (float*)(W + 39000000);
  float* he   = (float*)(W + 64600000);
  u16* Wtq    = (u16*)(W + 90200000);
  u16* Wtk    = Wtq + 128 * 128;
  u16* Wt1    = Wtk + 128 * 128;
  u16* Wt2    = Wt1 + 256 * 128;
  int* deg    = (int*)(W + 90400000);
  int* off    = deg + (NN + 1);
  int* cursor = off + (NN + 1);
  int* eids   = cursor + (NN + 1);

  hipMemsetAsync(deg, 0, (size_t)(NN + 1) * 4, stream);

  // fused prep (cvt + 4x wprep + csr count)
  prep_k<<<15384, 256, 0, stream>>>(node, (unsigned*)node16, Wq, Wk, W1, W2,
                                    Wtq, Wtk, Wt1, Wt2, dst, deg);
  scan_k<<<1, 1024, 0, stream>>>(deg, off, cursor);
  csr_fill_k<<<(NE + 255) / 256, 256, 0, stream>>>(dst, cursor, eids);

  const int ntiles = (NN + 63) / 64;  // 782

  // q/k projection (MFMA, swizzled LDS)
  qk_mfma_k<<<ntiles, 256, 0, stream>>>(node16, Wtq, Wtk, qb16, kb16);

  // edge exp in CSR order (coalesced writes)
  edge_exp_k<<<(NE * NH + 255) / 256, 256, 0, stream>>>(
      (const unsigned*)kb16, (const unsigned*)qb16, ba, src, dst, Wdis, eids, exs);

  // per-node attention + gate + LN1
  node_attn_k<<<3125, 512, 0, stream>>>(bond, Wv, exs, off, eids, node,
                                        Wb, g1, b1, he, (unsigned*)hbuf16);

  // fused FFN + residual + final LN
  ffn_mfma_k<<<ntiles, 256, 0, stream>>>(hbuf16, Wt1, Wt2, he, out);
}

// Round 7
// 814.357 us; speedup vs baseline: 2.3736x; 1.0198x over previous
//
#include <hip/hip_runtime.h>
#include <math.h>

#define NN 50000
#define NE 640000
#define DIM 128
#define NH 8

typedef unsigned short u16;
typedef __attribute__((ext_vector_type(8))) short short8;
typedef __attribute__((ext_vector_type(4))) float f32x4;

__device__ __forceinline__ float wave_sum64(float v) {
  #pragma unroll
  for (int m = 32; m >= 1; m >>= 1) v += __shfl_xor(v, m, 64);
  return v;
}
__device__ __forceinline__ unsigned bf16pk(float a, float b) {
  unsigned ua = __float_as_uint(a); ua = (ua + 0x7fffu + ((ua >> 16) & 1u)) >> 16;
  unsigned ub = __float_as_uint(b); ub = (ub + 0x7fffu + ((ub >> 16) & 1u)) & 0xffff0000u;
  return ua | ub;
}
__device__ __forceinline__ u16 bf16c(float x) {
  unsigned u = __float_as_uint(x);
  return (u16)((u + 0x7fffu + ((u >> 16) & 1u)) >> 16);
}
__device__ __forceinline__ float bf_lo(unsigned v) { return __uint_as_float(v << 16); }
__device__ __forceinline__ float bf_hi(unsigned v) { return __uint_as_float(v & 0xffff0000u); }

#define AS1(p) ((const __attribute__((address_space(1))) unsigned*)(p))
#define AS3(p) ((__attribute__((address_space(3))) unsigned*)(p))

// ---------------------------------------------------------------------------
// Fused prep: node f32->bf16 pack, 4x weight transpose+cvt, CSR degree count
// ---------------------------------------------------------------------------
__global__ __launch_bounds__(256) void prep_k(
    const float* __restrict__ node, unsigned* __restrict__ node16,
    const float* __restrict__ Wq, const float* __restrict__ Wk,
    const float* __restrict__ W1, const float* __restrict__ W2,
    u16* __restrict__ Wtq, u16* __restrict__ Wtk,
    u16* __restrict__ Wt1, u16* __restrict__ Wt2,
    const int* __restrict__ dst, int* __restrict__ deg) {
  int b = blockIdx.x, tid = threadIdx.x;
  if (b < 12500) {
    int t = b * 256 + tid;                    // t < 3,200,000 exactly
    float2 v = *(const float2*)(node + (size_t)2 * t);
    node16[t] = bf16pk(v.x, v.y);
  } else if (b < 12564) {
    int t = (b - 12500) * 256 + tid;          // 128x128
    int n = t >> 7, k = t & 127;
    Wtq[t] = bf16c(Wq[(size_t)k * 128 + n]);
  } else if (b < 12628) {
    int t = (b - 12564) * 256 + tid;
    int n = t >> 7, k = t & 127;
    Wtk[t] = bf16c(Wk[(size_t)k * 128 + n]);
  } else if (b < 12756) {
    int t = (b - 12628) * 256 + tid;          // K=128,N=256
    int n = t >> 7, k = t & 127;
    Wt1[t] = bf16c(W1[(size_t)k * 256 + n]);
  } else if (b < 12884) {
    int t = (b - 12756) * 256 + tid;          // K=256,N=128
    int n = t >> 8, k = t & 255;
    Wt2[t] = bf16c(W2[(size_t)k * 128 + n]);
  } else {
    int e = (b - 12884) * 256 + tid;          // e < 640,000 exactly
    atomicAdd(&deg[dst[e]], 1);
  }
}

// ---------------------------------------------------------------------------
// Coalesced single-block scan: 49 rounds of 1024, wave shfl-scan + LDS
// cross-wave scan + running base.
// ---------------------------------------------------------------------------
#define NROUND 49
__global__ __launch_bounds__(1024) void scan_k(const int* __restrict__ deg,
                                               int* __restrict__ off,
                                               int* __restrict__ cursor) {
  __shared__ int wsum[16];
  __shared__ int roundbase;
  int t = threadIdx.x;
  int lane = t & 63, w = t >> 6;
  if (t == 0) roundbase = 0;
  __syncthreads();
  for (int r = 0; r < NROUND; ++r) {
    int i = r * 1024 + t;
    int v = (i < NN) ? deg[i] : 0;
    int s = v;
    #pragma unroll
    for (int m = 1; m < 64; m <<= 1) {
      int u = __shfl_up(s, m, 64);
      if (lane >= m) s += u;
    }
    if (lane == 63) wsum[w] = s;
    __syncthreads();                       // [A] wsum raw
    if (w == 0) {
      int ws = (lane < 16) ? wsum[lane] : 0;
      #pragma unroll
      for (int m = 1; m < 16; m <<= 1) {
        int u = __shfl_up(ws, m, 64);
        if (lane >= m) ws += u;
      }
      if (lane < 16) wsum[lane] = ws;      // inclusive
    }
    __syncthreads();                       // [B] wsum scanned
    int base = roundbase + ((w > 0) ? wsum[w - 1] : 0);
    int excl = base + s - v;
    if (i < NN) { off[i] = excl; cursor[i] = excl; }
    __syncthreads();                       // [C] all read roundbase/wsum
    if (t == 0) roundbase += wsum[15];
    __syncthreads();                       // [D] roundbase updated
  }
  if (t == 0) off[NN] = roundbase;
}

__global__ __launch_bounds__(256) void csr_fill_k(const int* __restrict__ dst,
                                                  int* __restrict__ cursor,
                                                  int* __restrict__ eids) {
  int e = blockIdx.x * 256 + threadIdx.x;
  if (e < NE) {
    int p = atomicAdd(&cursor[dst[e]], 1);
    eids[p] = e;
  }
}

// ---------------------------------------------------------------------------
// MFMA GEMM: qb16/kb16 = node16 @ Wq / Wk  (M=NN, K=128, N=128+128)
// T2 swizzle: linear LDS dest via global_load_lds with pre-swizzled SOURCE;
// ds_read addresses XOR (row&7)<<4.
// ---------------------------------------------------------------------------
__global__ __launch_bounds__(256) void qk_mfma_k(
    const u16* __restrict__ A, const u16* __restrict__ Wtq,
    const u16* __restrict__ Wtk, u16* __restrict__ qo,
    u16* __restrict__ ko) {
  __shared__ u16 At[64 * 128];  // 16 KB
  const int wid = threadIdx.x >> 6, l = threadIdx.x & 63;
  const int quad = l >> 4, l16 = l & 15;
  const int c0 = (wid & 1) * 64;
  const u16* wt = (wid < 2) ? Wtq : Wtk;
  u16* ob = (wid < 2) ? qo : ko;
  short8 bfr[4][4];
  #pragma unroll
  for (int ct = 0; ct < 4; ++ct)
    #pragma unroll
    for (int ks = 0; ks < 4; ++ks)
      bfr[ct][ks] = *(const short8*)(wt + (c0 + ct * 16 + l16) * 128 + ks * 32 + quad * 8);
  const int ntiles = (NN + 63) / 64;
  for (int t = blockIdx.x; t < ntiles; t += gridDim.x) {
    const char* gsrc = (const char*)A + (size_t)t * 64 * 128 * 2;
    #pragma unroll
    for (int i = 0; i < 4; ++i) {
      int dbase = wid * 4096 + i * 1024;
      int soff = (dbase + l * 16) ^ ((((i * 4) + (l >> 4)) & 7) << 4);
      __builtin_amdgcn_global_load_lds(AS1(gsrc + soff),
                                       AS3((char*)At + dbase), 16, 0, 0);
    }
    __syncthreads();
    f32x4 acc[4][4];
    #pragma unroll
    for (int rt = 0; rt < 4; ++rt)
      #pragma unroll
      for (int ct = 0; ct < 4; ++ct)
        acc[rt][ct] = (f32x4){0.f, 0.f, 0.f, 0.f};
    #pragma unroll
    for (int ks = 0; ks < 4; ++ks) {
      short8 af[4];
      #pragma unroll
      for (int rt = 0; rt < 4; ++rt) {
        int bo = (((rt * 16 + l16) * 128 + ks * 32 + quad * 8) * 2) ^ ((l16 & 7) << 4);
        af[rt] = *(const short8*)((const char*)At + bo);
      }
      #pragma unroll
      for (int rt = 0; rt < 4; ++rt)
        #pragma unroll
        for (int ct = 0; ct < 4; ++ct)
          acc[rt][ct] = __builtin_amdgcn_mfma_f32_16x16x32_bf16(
              af[rt], bfr[ct][ks], acc[rt][ct], 0, 0, 0);
    }
    __syncthreads();
    #pragma unroll
    for (int rt = 0; rt < 4; ++rt)
      #pragma unroll
      for (int r = 0; r < 4; ++r) {
        int row = t * 64 + rt * 16 + quad * 4 + r;
        if (row < NN) {
          u16* op = ob + (size_t)row * 128 + c0 + l16;
          #pragma unroll
          for (int ct = 0; ct < 4; ++ct) op[ct * 16] = bf16c(acc[rt][ct][r]);
        }
      }
  }
}

// ---------------------------------------------------------------------------
// Fused FFN + final LN: out = LN(relu(hbuf16 @ W1) @ W2 + he)
// ---------------------------------------------------------------------------
__global__ __launch_bounds__(256) void ffn_mfma_k(
    const u16* __restrict__ A, const u16* __restrict__ Wt1,
    const u16* __restrict__ Wt2, const float* __restrict__ he,
    float* __restrict__ outp) {
  __shared__ __align__(16) u16 At[64 * 128];   // 16 KB
  __shared__ __align__(16) u16 Ht[64 * 256];   // 32 KB (swizzled)
  __shared__ float redS[4][64], redQ[4][64];   // 2 KB
  const int wid = threadIdx.x >> 6, l = threadIdx.x & 63;
  const int quad = l >> 4, l16 = l & 15;
  const int c1 = wid * 64;                     // W1 cols of 256
  const int c2 = wid * 32;                     // W2 cols of 128
  const int ntiles = (NN + 63) / 64;
  for (int t = blockIdx.x; t < ntiles; t += gridDim.x) {
    short8 b1f[4][4];
    #pragma unroll
    for (int ct = 0; ct < 4; ++ct)
      #pragma unroll
      for (int ks = 0; ks < 4; ++ks)
        b1f[ct][ks] = *(const short8*)(Wt1 + (c1 + ct * 16 + l16) * 128 + ks * 32 + quad * 8);
    const char* gsrc = (const char*)A + (size_t)t * 64 * 128 * 2;
    #pragma unroll
    for (int i = 0; i < 4; ++i) {
      int dbase = wid * 4096 + i * 1024;
      int soff = (dbase + l * 16) ^ ((((i * 4) + (l >> 4)) & 7) << 4);
      __builtin_amdgcn_global_load_lds(AS1(gsrc + soff),
                                       AS3((char*)At + dbase), 16, 0, 0);
    }
    __syncthreads();                           // [S]
    f32x4 acc1[4][4];
    #pragma unroll
    for (int rt = 0; rt < 4; ++rt)
      #pragma unroll
      for (int ct = 0; ct < 4; ++ct)
        acc1[rt][ct] = (f32x4){0.f, 0.f, 0.f, 0.f};
    #pragma unroll
    for (int ks = 0; ks < 4; ++ks) {
      short8 af[4];
      #pragma unroll
      for (int rt = 0; rt < 4; ++rt) {
        int bo = (((rt * 16 + l16) * 128 + ks * 32 + quad * 8) * 2) ^ ((l16 & 7) << 4);
        af[rt] = *(const short8*)((const char*)At + bo);
      }
      #pragma unroll
      for (int rt = 0; rt < 4; ++rt)
        #pragma unroll
        for (int ct = 0; ct < 4; ++ct)
          acc1[rt][ct] = __builtin_amdgcn_mfma_f32_16x16x32_bf16(
              af[rt], b1f[ct][ks], acc1[rt][ct], 0, 0, 0);
    }
    #pragma unroll
    for (int rt = 0; rt < 4; ++rt)
      #pragma unroll
      for (int r = 0; r < 4; ++r) {
        int row = rt * 16 + quad * 4 + r;
        #pragma unroll
        for (int ct = 0; ct < 4; ++ct) {
          int col = c1 + ct * 16 + l16;
          int bo = (row * 512 + col * 2) ^ ((row & 7) << 4);
          *(u16*)((char*)Ht + bo) = bf16c(fmaxf(acc1[rt][ct][r], 0.f));
        }
      }
    __syncthreads();                           // [H]
    short8 b2f[2][8];
    #pragma unroll
    for (int ct = 0; ct < 2; ++ct)
      #pragma unroll
      for (int ks = 0; ks < 8; ++ks)
        b2f[ct][ks] = *(const short8*)(Wt2 + (c2 + ct * 16 + l16) * 256 + ks * 32 + quad * 8);
    f32x4 acc2[4][2];
    #pragma unroll
    for (int rt = 0; rt < 4; ++rt)
      #pragma unroll
      for (int ct = 0; ct < 2; ++ct)
        acc2[rt][ct] = (f32x4){0.f, 0.f, 0.f, 0.f};
    #pragma unroll
    for (int ks = 0; ks < 8; ++ks) {
      short8 af[4];
      #pragma unroll
      for (int rt = 0; rt < 4; ++rt) {
        int bo = ((rt * 16 + l16) * 512 + ks * 64 + quad * 16) ^ ((l16 & 7) << 4);
        af[rt] = *(const short8*)((const char*)Ht + bo);
      }
      #pragma unroll
      for (int rt = 0; rt < 4; ++rt)
        #pragma unroll
        for (int ct = 0; ct < 2; ++ct)
          acc2[rt][ct] = __builtin_amdgcn_mfma_f32_16x16x32_bf16(
              af[rt], b2f[ct][ks], acc2[rt][ct], 0, 0, 0);
    }
    #pragma unroll
    for (int rt = 0; rt < 4; ++rt)
      #pragma unroll
      for (int r = 0; r < 4; ++r) {
        int row = rt * 16 + quad * 4 + r;
        int grow = t * 64 + row;
        float h0 = 0.f, h1 = 0.f;
        if (grow < NN) {
          h0 = he[(size_t)grow * 128 + c2 + l16];
          h1 = he[(size_t)grow * 128 + c2 + 16 + l16];
        }
        float z0 = acc2[rt][0][r] + h0;
        float z1 = acc2[rt][1][r] + h1;
        acc2[rt][0][r] = z0; acc2[rt][1][r] = z1;
        float ps = z0 + z1;
        float pq = fmaf(z0, z0, z1 * z1);
        ps += __shfl_xor(ps, 1, 64);  pq += __shfl_xor(pq, 1, 64);
        ps += __shfl_xor(ps, 2, 64);  pq += __shfl_xor(pq, 2, 64);
        ps += __shfl_xor(ps, 4, 64);  pq += __shfl_xor(pq, 4, 64);
        ps += __shfl_xor(ps, 8, 64);  pq += __shfl_xor(pq, 8, 64);
        if (l16 == 0) { redS[wid][row] = ps; redQ[wid][row] = pq; }
      }
    __syncthreads();                           // [R]
    #pragma unroll
    for (int rt = 0; rt < 4; ++rt)
      #pragma unroll
      for (int r = 0; r < 4; ++r) {
        int row = rt * 16 + quad * 4 + r;
        int grow = t * 64 + row;
        float s4 = redS[0][row] + redS[1][row] + redS[2][row] + redS[3][row];
        float q4 = redQ[0][row] + redQ[1][row] + redQ[2][row] + redQ[3][row];
        float mu = s4 * (1.f / 128.f);
        float vr = q4 * (1.f / 128.f) - mu * mu;
        float rs = rsqrtf(vr + 1e-5f);
        if (grow < NN) {
          outp[(size_t)grow * 128 + c2 + l16]      = (acc2[rt][0][r] - mu) * rs;
          outp[(size_t)grow * 128 + c2 + 16 + l16] = (acc2[rt][1][r] - mu) * rs;
        }
      }
  }
}

// ---------------------------------------------------------------------------
// Edge exp in CSR order: exs[p*8+h] = exp(dot(k[src],q[dst])_h/4 + ba*Wdis)
// coalesced writes; e = eids[p].  (no max-subtraction: logits bounded)
// ---------------------------------------------------------------------------
__global__ __launch_bounds__(256) void edge_exp_k(
    const unsigned* __restrict__ kb16, const unsigned* __restrict__ qb16,
    const float* __restrict__ ba, const int* __restrict__ src,
    const int* __restrict__ dst, const float* __restrict__ Wdis,
    const int* __restrict__ eids, float* __restrict__ exs) {
  int idx = blockIdx.x * 256 + threadIdx.x;
  if (idx >= NE * NH) return;
  int p = idx >> 3, h = idx & 7;
  int e = eids[p];
  int s = src[e], t = dst[e];
  const uint4* kp = (const uint4*)(kb16 + (size_t)s * 64 + h * 8);
  const uint4* qp = (const uint4*)(qb16 + (size_t)t * 64 + h * 8);
  uint4 A0 = kp[0], A1 = kp[1];
  uint4 B0 = qp[0], B1 = qp[1];
  float sc = 0.f;
  sc = fmaf(bf_lo(A0.x), bf_lo(B0.x), sc); sc = fmaf(bf_hi(A0.x), bf_hi(B0.x), sc);
  sc = fmaf(bf_lo(A0.y), bf_lo(B0.y), sc); sc = fmaf(bf_hi(A0.y), bf_hi(B0.y), sc);
  sc = fmaf(bf_lo(A0.z), bf_lo(B0.z), sc); sc = fmaf(bf_hi(A0.z), bf_hi(B0.z), sc);
  sc = fmaf(bf_lo(A0.w), bf_lo(B0.w), sc); sc = fmaf(bf_hi(A0.w), bf_hi(B0.w), sc);
  sc = fmaf(bf_lo(A1.x), bf_lo(B1.x), sc); sc = fmaf(bf_hi(A1.x), bf_hi(B1.x), sc);
  sc = fmaf(bf_lo(A1.y), bf_lo(B1.y), sc); sc = fmaf(bf_hi(A1.y), bf_hi(B1.y), sc);
  sc = fmaf(bf_lo(A1.z), bf_lo(B1.z), sc); sc = fmaf(bf_hi(A1.z), bf_hi(B1.z), sc);
  sc = fmaf(bf_lo(A1.w), bf_lo(B1.w), sc); sc = fmaf(bf_hi(A1.w), bf_hi(B1.w), sc);
  exs[idx] = __expf(sc * 0.25f + ba[e] * Wdis[h]);
}

// ---------------------------------------------------------------------------
// Per-node: weighted bond gather (depth-8 static unroll, zero scratch),
// denominator folded in, Wv projection (LDS), beta gate + LN1.
// 1024 thr = 16 waves/block; LDS exactly 64 KB -> 2 blocks/CU = 32 waves/CU.
// gbuf unpadded: writes are stride-1, reads are 16-lane-group broadcasts.
// ---------------------------------------------------------------------------
__global__ __launch_bounds__(1024, 8) void node_attn_k(
    const float* __restrict__ bond, const float* __restrict__ WvG,
    const float* __restrict__ exs, const int* __restrict__ off,
    const int* __restrict__ eids, const float* __restrict__ x,
    const float* __restrict__ Wb, const float* __restrict__ g1,
    const float* __restrict__ b1, float* __restrict__ he,
    unsigned* __restrict__ hbuf16) {
  __shared__ unsigned Wvpk[DIM * 64];       // 32 KB, packed cols (c, c+64)
  __shared__ unsigned gbuf[16][NH][64];     // 32 KB, wave-private rows
  for (int t = threadIdx.x; t < DIM * 64; t += 1024) {
    int i = t >> 6, c = t & 63;
    Wvpk[t] = bf16pk(WvG[i * DIM + c], WvG[i * DIM + c + 64]);
  }
  __syncthreads();
  const int wid = threadIdx.x >> 6, l = threadIdx.x & 63;
  const int hh = l & 7;
  const float wb0 = Wb[l],         wb1 = Wb[l + 64];
  const float wb2 = Wb[DIM + l],   wb3 = Wb[DIM + l + 64];
  const float wb4 = Wb[2*DIM + l], wb5 = Wb[2*DIM + l + 64];
  const float gl0 = g1[l], gl1 = g1[l + 64];
  const float bl0 = b1[l], bl1 = b1[l + 64];

  for (int n = blockIdx.x * 16 + wid; n < NN; n += gridDim.x * 16) {
    int o0 = __builtin_amdgcn_readfirstlane(off[n]);
    int o1 = __builtin_amdgcn_readfirstlane(off[n + 1]);
    int deg = o1 - o0;
    float acc[16];
    #pragma unroll
    for (int i = 0; i < 16; ++i) acc[i] = 0.f;
    float d0 = 0.f, d1 = 0.f, d2 = 0.f, d3 = 0.f;
    float d4 = 0.f, d5 = 0.f, d6 = 0.f, d7 = 0.f;

    for (int g = 0; g < deg; g += 8) {
      float2 bc[8];
      #pragma unroll
      for (int s = 0; s < 8; ++s) {
        if (g + s < deg) {
          int e = eids[o0 + g + s];
          bc[s] = *(const float2*)(bond + (size_t)e * DIM + 2 * l);
        }
      }
      #pragma unroll
      for (int s = 0; s < 8; ++s) {
        if (g + s < deg) {
          const float4* ep = (const float4*)(exs) + (size_t)(o0 + g + s) * 2;
          float4 ea = ep[0], eb = ep[1];   // wave-uniform, L1-hot
          d0 += ea.x; d1 += ea.y; d2 += ea.z; d3 += ea.w;
          d4 += eb.x; d5 += eb.y; d6 += eb.z; d7 += eb.w;
          float2 bv = bc[s];
          acc[0]  = fmaf(ea.x, bv.x, acc[0]);  acc[1]  = fmaf(ea.x, bv.y, acc[1]);
          acc[2]  = fmaf(ea.y, bv.x, acc[2]);  acc[3]  = fmaf(ea.y, bv.y, acc[3]);
          acc[4]  = fmaf(ea.z, bv.x, acc[4]);  acc[5]  = fmaf(ea.z, bv.y, acc[5]);
          acc[6]  = fmaf(ea.w, bv.x, acc[6]);  acc[7]  = fmaf(ea.w, bv.y, acc[7]);
          acc[8]  = fmaf(eb.x, bv.x, acc[8]);  acc[9]  = fmaf(eb.x, bv.y, acc[9]);
          acc[10] = fmaf(eb.y, bv.x, acc[10]); acc[11] = fmaf(eb.y, bv.y, acc[11]);
          acc[12] = fmaf(eb.z, bv.x, acc[12]); acc[13] = fmaf(eb.z, bv.y, acc[13]);
          acc[14] = fmaf(eb.w, bv.x, acc[14]); acc[15] = fmaf(eb.w, bv.y, acc[15]);
        }
      }
    }
    // select this lane's head denominator (hh = l&7), normalize
    float dsa = (hh & 1) ? d1 : d0, dsb = (hh & 1) ? d3 : d2;
    float dsc = (hh & 1) ? d5 : d4, dsd = (hh & 1) ? d7 : d6;
    float dse = (hh & 2) ? dsb : dsa, dsf = (hh & 2) ? dsd : dsc;
    float dsel = (hh & 4) ? dsf : dse;
    float rden = 1.f / (dsel + 1e-16f);
    #pragma unroll
    for (int h = 0; h < 8; ++h) {
      float rh = __shfl(rden, h, 64);
      acc[2 * h] *= rh; acc[2 * h + 1] *= rh;
    }
    // stash g (bf16-packed), wave-private row -> no barrier
    #pragma unroll
    for (int h = 0; h < 8; ++h)
      gbuf[wid][h][l] = bf16pk(acc[2 * h], acc[2 * h + 1]);
    // projection: ft cols (l, l+64); heads h0 = l>>4, h1 = 4 + (l>>4)
    int h0 = l >> 4, h1 = 4 + (l >> 4);
    float f0 = 0.f, f1 = 0.f;
    #pragma unroll 8
    for (int ii = 0; ii < 64; ++ii) {
      unsigned u = gbuf[wid][h0][ii];
      unsigned v = gbuf[wid][h1][ii];
      unsigned w0 = Wvpk[(2 * ii) * 64 + l];
      unsigned w1 = Wvpk[(2 * ii + 1) * 64 + l];
      f0 = fmaf(bf_lo(u), bf_lo(w0), f0); f0 = fmaf(bf_hi(u), bf_lo(w1), f0);
      f1 = fmaf(bf_lo(v), bf_hi(w0), f1); f1 = fmaf(bf_hi(v), bf_hi(w1), f1);
    }
    // beta gate + LN1
    float x0 = x[(size_t)n * DIM + l], x1 = x[(size_t)n * DIM + l + 64];
    float s = f0 * wb0 + x0 * wb2 + (f0 - x0) * wb4
            + f1 * wb1 + x1 * wb3 + (f1 - x1) * wb5;
    s = wave_sum64(s);
    float beta = 1.f / (1.f + __expf(-s));
    float he0 = beta * x0 + (1.f - beta) * f0;
    float he1 = beta * x1 + (1.f - beta) * f1;
    he[(size_t)n * DIM + l] = he0;
    he[(size_t)n * DIM + l + 64] = he1;
    float mu = wave_sum64(he0 + he1) * (1.f / DIM);
    float vr = wave_sum64(he0 * he0 + he1 * he1) * (1.f / DIM) - mu * mu;
    float rs = rsqrtf(vr + 1e-5f);
    float v0 = (he0 - mu) * rs * gl0 + bl0;
    float v1 = (he1 - mu) * rs * gl1 + bl1;
    // shuffle-transpose to packed bf16 row layout: uint l holds cols (2l,2l+1)
    int i0 = (2 * l) & 63, i1 = (2 * l + 1) & 63;
    float a0 = __shfl(v0, i0, 64), b0 = __shfl(v1, i0, 64);
    float a1 = __shfl(v0, i1, 64), b1v = __shfl(v1, i1, 64);
    float c0 = (l < 32) ? a0 : b0;
    float c1 = (l < 32) ? a1 : b1v;
    hbuf16[(size_t)n * 64 + l] = bf16pk(c0, c1);
  }
}

// ---------------------------------------------------------------------------
extern "C" void kernel_launch(void* const* d_in, const int* in_sizes, int n_in,
                              void* d_out, int out_size, void* d_ws, size_t ws_size,
                              hipStream_t stream) {
  const float* node = (const float*)d_in[0];
  const float* bond = (const float*)d_in[1];
  const float* ba   = (const float*)d_in[2];
  const int*   src  = (const int*)  d_in[3];
  const int*   dst  = (const int*)  d_in[4];
  const float* Wk   = (const float*)d_in[5];
  const float* Wq   = (const float*)d_in[6];
  const float* Wv   = (const float*)d_in[7];
  const float* Wdis = (const float*)d_in[8];
  const float* Wb   = (const float*)d_in[9];
  const float* g1   = (const float*)d_in[10];
  const float* b1   = (const float*)d_in[11];
  const float* W1   = (const float*)d_in[12];
  const float* W2   = (const float*)d_in[13];
  float* out = (float*)d_out;

  // workspace byte layout (identical to the 858/830-us passing runs):
  char* W = (char*)d_ws;
  u16* node16 = (u16*)(W);
  u16* qb16   = (u16*)(W + 13000000);
  u16* kb16   = (u16*)(W + 26000000);
  u16* hbuf16 = (u16*)(W + 26000000);
  float* exs  = (float*)(W + 39000000);
  float* he   = (float*)(W + 64600000);
  u16* Wtq    = (u16*)(W + 90200000);
  u16* Wtk    = Wtq + 128 * 128;
  u16* Wt1    = Wtk + 128 * 128;
  u16* Wt2    = Wt1 + 256 * 128;
  int* deg    = (int*)(W + 90400000);
  int* off    = deg + (NN + 1);
  int* cursor = off + (NN + 1);
  int* eids   = cursor + (NN + 1);

  hipMemsetAsync(deg, 0, (size_t)(NN + 1) * 4, stream);

  // fused prep (cvt + 4x wprep + csr count)
  prep_k<<<15384, 256, 0, stream>>>(node, (unsigned*)node16, Wq, Wk, W1, W2,
                                    Wtq, Wtk, Wt1, Wt2, dst, deg);
  scan_k<<<1, 1024, 0, stream>>>(deg, off, cursor);
  csr_fill_k<<<(NE + 255) / 256, 256, 0, stream>>>(dst, cursor, eids);

  const int ntiles = (NN + 63) / 64;  // 782

  // q/k projection (MFMA, swizzled LDS)
  qk_mfma_k<<<ntiles, 256, 0, stream>>>(node16, Wtq, Wtk, qb16, kb16);

  // edge exp in CSR order (coalesced writes)
  edge_exp_k<<<(NE * NH + 255) / 256, 256, 0, stream>>>(
      (const unsigned*)kb16, (const unsigned*)qb16, ba, src, dst, Wdis, eids, exs);

  // per-node attention + gate + LN1 (16 waves/block, 2 blocks/CU)
  node_attn_k<<<3125, 1024, 0, stream>>>(bond, Wv, exs, off, eids, node,
                                         Wb, g1, b1, he, (unsigned*)hbuf16);

  // fused FFN + residual + final LN
  ffn_mfma_k<<<ntiles, 256, 0, stream>>>(hbuf16, Wt1, Wt2, he, out);
}